// Round 1
// baseline (241.771 us; speedup 1.0000x reference)
//
#include <hip/hip_runtime.h>
#include <hip/hip_bf16.h>

typedef __bf16 bf16x8 __attribute__((ext_vector_type(8)));
typedef __bf16 bf16x4 __attribute__((ext_vector_type(4)));
typedef float  f32x4  __attribute__((ext_vector_type(4)));

#define DM 1024
#define PD 3328
#define TROWS 8192   // bs*seq = 2*4096
#define SEQ 4096

__device__ __forceinline__ float sigmoidf(float x) { return 1.f / (1.f + __expf(-x)); }

__device__ __forceinline__ void gload16(const void* g, void* l) {
  __builtin_amdgcn_global_load_lds(
      (const __attribute__((address_space(1))) void*)g,
      (__attribute__((address_space(3))) void*)l, 16, 0, 0);
}

// ---------------- transpose + f32->bf16 convert:  in[K][N] f32 -> out[N][K] bf16
__global__ __launch_bounds__(256) void tcvt_kernel(const float* __restrict__ in,
                                                   __bf16* __restrict__ out,
                                                   int K, int N) {
  __shared__ float tile[32][33];
  int n0 = blockIdx.x * 32, k0 = blockIdx.y * 32;
  int tx = threadIdx.x, ty = threadIdx.y;     // 32 x 8
  for (int i = ty; i < 32; i += 8) tile[i][tx] = in[(size_t)(k0 + i) * N + n0 + tx];
  __syncthreads();
  for (int i = ty; i < 32; i += 8) out[(size_t)(n0 + i) * K + k0 + tx] = (__bf16)tile[tx][i];
}

// ---------------- RMSNorm -> bf16
__global__ __launch_bounds__(256) void rmsnorm_kernel(const float* __restrict__ hidden,
                                                      const float* __restrict__ w,
                                                      __bf16* __restrict__ hbf) {
  int r = blockIdx.x;
  int tid = threadIdx.x;
  float4 v = ((const float4*)(hidden + (size_t)r * DM))[tid];
  float ss = v.x * v.x + v.y * v.y + v.z * v.z + v.w * v.w;
#pragma unroll
  for (int off = 32; off > 0; off >>= 1) ss += __shfl_xor(ss, off);
  __shared__ float wsum[4];
  int lane = tid & 63, wid = tid >> 6;
  if (lane == 0) wsum[wid] = ss;
  __syncthreads();
  float tot = wsum[0] + wsum[1] + wsum[2] + wsum[3];
  float inv = rsqrtf(tot * (1.f / 1024.f) + 1e-6f);
  float4 wl = ((const float4*)w)[tid];
  bf16x4 o;
  o[0] = (__bf16)(v.x * inv * wl.x);
  o[1] = (__bf16)(v.y * inv * wl.y);
  o[2] = (__bf16)(v.z * inv * wl.z);
  o[3] = (__bf16)(v.w * inv * wl.w);
  *(bf16x4*)(hbf + (size_t)r * DM + tid * 4) = o;
}

// ---------------- 128x128 MFMA GEMM (m97 structure): A[M][K] bf16, Bt[N][K] bf16
// EPI 1: split epilogue (z/x/g/q/k).  EPI 0: out = acc + shortcut (f32).
template <int EPI>
__global__ __launch_bounds__(256) void gemm128_kernel(
    const __bf16* __restrict__ A, const __bf16* __restrict__ Bt, int K,
    const float* __restrict__ gate_bias, const float* __restrict__ shortcut,
    float* __restrict__ outf, __bf16* __restrict__ zbf, float* __restrict__ xf,
    float* __restrict__ gf, __bf16* __restrict__ qbf, float* __restrict__ kf) {
  __shared__ __bf16 As[128 * 64];
  __shared__ __bf16 Bs[128 * 64];
  const int tid = threadIdx.x;
  const int lane = tid & 63, wid = tid >> 6;
  const int wr = wid >> 1, wc = wid & 1;
  const int m0 = blockIdx.y * 128, n0 = blockIdx.x * 128;

  f32x4 acc[4][4] = {};

  for (int kt = 0; kt < K; kt += 64) {
#pragma unroll
    for (int it = 0; it < 4; ++it) {
      int idx = tid + it * 256;          // 16B unit index
      int row = idx >> 3, cu = idx & 7;
      gload16(&A[(size_t)(m0 + row) * K + kt + cu * 8], &As[idx * 8]);
      gload16(&Bt[(size_t)(n0 + row) * K + kt + cu * 8], &Bs[idx * 8]);
    }
    __syncthreads();
#pragma unroll
    for (int kk = 0; kk < 64; kk += 32) {
      bf16x8 af[4], bfr[4];
#pragma unroll
      for (int mi = 0; mi < 4; ++mi)
        af[mi] = *(const bf16x8*)&As[(wr * 64 + mi * 16 + (lane & 15)) * 64 + kk + (lane >> 4) * 8];
#pragma unroll
      for (int ni = 0; ni < 4; ++ni)
        bfr[ni] = *(const bf16x8*)&Bs[(wc * 64 + ni * 16 + (lane & 15)) * 64 + kk + (lane >> 4) * 8];
#pragma unroll
      for (int mi = 0; mi < 4; ++mi)
#pragma unroll
        for (int ni = 0; ni < 4; ++ni)
          acc[mi][ni] = __builtin_amdgcn_mfma_f32_16x16x32_bf16(af[mi], bfr[ni], acc[mi][ni], 0, 0, 0);
    }
    __syncthreads();
  }

#pragma unroll
  for (int mi = 0; mi < 4; ++mi) {
#pragma unroll
    for (int ni = 0; ni < 4; ++ni) {
#pragma unroll
      for (int i = 0; i < 4; ++i) {
        int r = m0 + wr * 64 + mi * 16 + (lane >> 4) * 4 + i;
        int n = n0 + wc * 64 + ni * 16 + (lane & 15);
        float v = acc[mi][ni][i];
        if (EPI == 1) {
          if (n < 1024)       zbf[(size_t)r * DM + n] = (__bf16)sigmoidf(v);
          else if (n < 2048)  xf[(size_t)r * DM + (n - 1024)] = v;
          else if (n < 3072)  gf[(size_t)r * DM + (n - 2048)] = sigmoidf(v + gate_bias[n - 2048]);
          else if (n < 3200)  qbf[(size_t)r * 128 + (n - 3072)] = (__bf16)v;
          else                kf[(size_t)r * 128 + (n - 3200)] = v;
        } else {
          outf[(size_t)r * DM + n] = v + shortcut[(size_t)r * DM + n];
        }
      }
    }
  }
}

// ---------------- per-chunk first-order scan (f32 state), thread = one d-channel
// xk[t] = g[t]*xk[t-1] + (1-g[t])*in[t], reset each 64-chunk. Outputs bf16.
__global__ __launch_bounds__(256) void scan_kernel(const float* __restrict__ g,
                                                   const float* __restrict__ x,
                                                   const float* __restrict__ kraw,
                                                   __bf16* __restrict__ ixa,
                                                   __bf16* __restrict__ ika) {
  int bx = blockIdx.x;            // 2*64*4 = 512 blocks
  int part = bx & 3;
  int c = (bx >> 2) & 63;
  int b = bx >> 8;
  int d = part * 256 + threadIdx.x;
  size_t base = (size_t)b * SEQ + (size_t)c * 64;
  float sx = 0.f, sk = 0.f;
  for (int t = 0; t < 64; ++t) {
    size_t row = base + t;
    float gg = g[row * DM + d];
    float xv = x[row * DM + d];
    float kv = kraw[row * 128 + (d & 127)];
    sx = gg * (sx - xv) + xv;   // = g*prev + (1-g)*x
    sk = gg * (sk - kv) + kv;
    ixa[row * DM + d] = (__bf16)sx;
    ika[row * DM + d] = (__bf16)sk;
  }
}

// ---------------- attention: block = (qtile 64 queries, head, batch); 4 waves
__global__ __launch_bounds__(256) void attn_kernel(const __bf16* __restrict__ qbf,
                                                   const __bf16* __restrict__ ixa,
                                                   const __bf16* __restrict__ ika,
                                                   const __bf16* __restrict__ zbf,
                                                   __bf16* __restrict__ y) {
  const int qt = blockIdx.x;   // 0..63 query chunk
  const int h  = blockIdx.y;   // 0..15
  const int b  = blockIdx.z;   // 0..1
  const int tid = threadIdx.x;
  const int lane = tid & 63, wd = tid >> 6;

  __shared__ __bf16 qs[64 * 72];
  __shared__ __bf16 ck[64 * 72];
  __shared__ __bf16 cxT[64 * 72];
  __shared__ __bf16 pb[64 * 72];
  __shared__ float sc[64 * 65];
  __shared__ float rden[64], iwd[64];

  const size_t base = (size_t)b * SEQ;

  // stage Q rows and chunk_k rows (row-major [rows][64], pad 72)
  for (int i = tid; i < 512; i += 256) {
    int row = i >> 3, part = i & 7;
    *(bf16x8*)&qs[row * 72 + part * 8] =
        *(const bf16x8*)&qbf[(base + qt * 64 + row) * 128 + (h & 1) * 64 + part * 8];
    *(bf16x8*)&ck[row * 72 + part * 8] =
        *(const bf16x8*)&ika[(base + (size_t)row * 64) * DM + h * 64 + part * 8];
  }
  // stage chunk_x transposed: cxT[j][c]
  for (int i = tid; i < 4096; i += 256) {
    int c = i & 63, j = i >> 6;
    cxT[j * 72 + c] = ixa[(base + (size_t)c * 64) * DM + h * 64 + j];
  }
  __syncthreads();

  // scores = scale * Q . chunk_k^T  -> sc[q][c]
  {
    f32x4 d4[4] = {};
#pragma unroll
    for (int kk = 0; kk < 64; kk += 32) {
      bf16x8 a = *(const bf16x8*)&qs[(wd * 16 + (lane & 15)) * 72 + kk + (lane >> 4) * 8];
#pragma unroll
      for (int ni = 0; ni < 4; ++ni) {
        bf16x8 bb = *(const bf16x8*)&ck[(ni * 16 + (lane & 15)) * 72 + kk + (lane >> 4) * 8];
        d4[ni] = __builtin_amdgcn_mfma_f32_16x16x32_bf16(a, bb, d4[ni], 0, 0, 0);
      }
    }
#pragma unroll
    for (int ni = 0; ni < 4; ++ni)
#pragma unroll
      for (int i = 0; i < 4; ++i) {
        int qrow = wd * 16 + (lane >> 4) * 4 + i;
        int c = ni * 16 + (lane & 15);
        sc[qrow * 65 + c] = 0.125f * d4[ni][i];
      }
  }

  // intra_lse per query (global reads, independent of LDS)
  float lse = 0.f;
  if (tid < 64) {
    const __bf16* qrow = &qbf[(base + qt * 64 + tid) * 128 + (h & 1) * 64];
    const __bf16* krow = &ika[(base + qt * 64 + tid) * DM + h * 64];
    float dot = 0.f;
#pragma unroll
    for (int p = 0; p < 8; ++p) {
      bf16x8 qa = *(const bf16x8*)&qrow[p * 8];
      bf16x8 ka = *(const bf16x8*)&krow[p * 8];
#pragma unroll
      for (int e = 0; e < 8; ++e) dot += (float)qa[e] * (float)ka[e];
    }
    lse = 0.125f * dot;
  }
  __syncthreads();

  // softmax over allowed chunks c < qt, plus intra term
  if (tid < 64) {
    int q = tid;
    float m = lse;
    for (int c = 0; c < qt; ++c) m = fmaxf(m, sc[q * 65 + c]);
    float den = 0.f;
    for (int c = 0; c < 64; ++c) {
      float wv = (c < qt) ? __expf(sc[q * 65 + c] - m) : 0.f;
      pb[q * 72 + c] = (__bf16)wv;
      den += wv;
    }
    float iw = __expf(lse - m);
    den += iw;
    rden[q] = 1.f / den;
    iwd[q] = iw;
  }
  __syncthreads();

  // PV: out[q][j] = sum_c w[q][c] * chunk_x[c][j]
  {
    f32x4 d4[4] = {};
#pragma unroll
    for (int kk = 0; kk < 64; kk += 32) {
      bf16x8 a = *(const bf16x8*)&pb[(wd * 16 + (lane & 15)) * 72 + kk + (lane >> 4) * 8];
#pragma unroll
      for (int ni = 0; ni < 4; ++ni) {
        bf16x8 bb = *(const bf16x8*)&cxT[(ni * 16 + (lane & 15)) * 72 + kk + (lane >> 4) * 8];
        d4[ni] = __builtin_amdgcn_mfma_f32_16x16x32_bf16(a, bb, d4[ni], 0, 0, 0);
      }
    }
#pragma unroll
    for (int ni = 0; ni < 4; ++ni)
#pragma unroll
      for (int i = 0; i < 4; ++i) {
        int qrow = wd * 16 + (lane >> 4) * 4 + i;
        int j = ni * 16 + (lane & 15);
        size_t srow = base + qt * 64 + qrow;
        float ix = (float)ixa[srow * DM + h * 64 + j];
        float outv = (d4[ni][i] + iwd[qrow] * ix) * rden[qrow];
        float zv = (float)zbf[srow * DM + h * 64 + j];
        y[srow * DM + h * 64 + j] = (__bf16)(outv * zv);
      }
  }
}

// ---------------- launcher
extern "C" void kernel_launch(void* const* d_in, const int* in_sizes, int n_in,
                              void* d_out, int out_size, void* d_ws, size_t ws_size,
                              hipStream_t stream) {
  const float* hidden = (const float*)d_in[0];
  const float* rmsw   = (const float*)d_in[1];
  const float* Win    = (const float*)d_in[2];
  const float* gbias  = (const float*)d_in[3];
  const float* Wout   = (const float*)d_in[4];
  float* out = (float*)d_out;

  char* ws = (char*)d_ws;
  size_t o = 0;
  auto alloc = [&](size_t bytes) { char* p = ws + o; o += (bytes + 255) & ~(size_t)255; return p; };
  __bf16* WinT  = (__bf16*)alloc((size_t)PD * DM * 2);
  __bf16* WoutT = (__bf16*)alloc((size_t)DM * DM * 2);
  __bf16* hy    = (__bf16*)alloc((size_t)TROWS * DM * 2);  // h_bf, reused as y after GEMM1
  __bf16* zbf   = (__bf16*)alloc((size_t)TROWS * DM * 2);
  float*  xf    = (float*)alloc((size_t)TROWS * DM * 4);
  float*  gf    = (float*)alloc((size_t)TROWS * DM * 4);
  __bf16* qbf   = (__bf16*)alloc((size_t)TROWS * 128 * 2);
  float*  kf    = (float*)alloc((size_t)TROWS * 128 * 4);
  __bf16* ixa   = (__bf16*)alloc((size_t)TROWS * DM * 2);
  __bf16* ika   = (__bf16*)alloc((size_t)TROWS * DM * 2);

  tcvt_kernel<<<dim3(PD / 32, DM / 32), dim3(32, 8), 0, stream>>>(Win, WinT, DM, PD);
  tcvt_kernel<<<dim3(DM / 32, DM / 32), dim3(32, 8), 0, stream>>>(Wout, WoutT, DM, DM);
  rmsnorm_kernel<<<TROWS, 256, 0, stream>>>(hidden, rmsw, hy);
  gemm128_kernel<1><<<dim3(PD / 128, TROWS / 128), 256, 0, stream>>>(
      hy, WinT, DM, gbias, nullptr, nullptr, zbf, xf, gf, qbf, kf);
  scan_kernel<<<512, 256, 0, stream>>>(gf, xf, kf, ixa, ika);
  attn_kernel<<<dim3(64, 16, 2), 256, 0, stream>>>(qbf, ixa, ika, zbf, hy);
  gemm128_kernel<0><<<dim3(DM / 128, TROWS / 128), 256, 0, stream>>>(
      hy, WoutT, DM, nullptr, hidden, out, nullptr, nullptr, nullptr, nullptr, nullptr);
}

// Round 2
// 223.917 us; speedup vs baseline: 1.0797x; 1.0797x over previous
//
#include <hip/hip_runtime.h>
#include <hip/hip_bf16.h>

typedef __bf16 bf16x8 __attribute__((ext_vector_type(8)));
typedef __bf16 bf16x4 __attribute__((ext_vector_type(4)));
typedef float  f32x4  __attribute__((ext_vector_type(4)));

#define DM 1024
#define PD 3328
#define TROWS 8192   // bs*seq = 2*4096
#define SEQ 4096

__device__ __forceinline__ float sigmoidf(float x) { return 1.f / (1.f + __expf(-x)); }

__device__ __forceinline__ void gload16(const void* g, void* l) {
  __builtin_amdgcn_global_load_lds(
      (const __attribute__((address_space(1))) void*)g,
      (__attribute__((address_space(3))) void*)l, 16, 0, 0);
}

// ---------------- transpose + f32->bf16 convert:  in[K][N] f32 -> out[N][K] bf16
__global__ __launch_bounds__(256) void tcvt_kernel(const float* __restrict__ in,
                                                   __bf16* __restrict__ out,
                                                   int K, int N) {
  __shared__ float tile[32][33];
  int n0 = blockIdx.x * 32, k0 = blockIdx.y * 32;
  int tx = threadIdx.x, ty = threadIdx.y;     // 32 x 8
  for (int i = ty; i < 32; i += 8) tile[i][tx] = in[(size_t)(k0 + i) * N + n0 + tx];
  __syncthreads();
  for (int i = ty; i < 32; i += 8) out[(size_t)(n0 + i) * K + k0 + tx] = (__bf16)tile[tx][i];
}

// ---------------- RMSNorm -> bf16
__global__ __launch_bounds__(256) void rmsnorm_kernel(const float* __restrict__ hidden,
                                                      const float* __restrict__ w,
                                                      __bf16* __restrict__ hbf) {
  int r = blockIdx.x;
  int tid = threadIdx.x;
  float4 v = ((const float4*)(hidden + (size_t)r * DM))[tid];
  float ss = v.x * v.x + v.y * v.y + v.z * v.z + v.w * v.w;
#pragma unroll
  for (int off = 32; off > 0; off >>= 1) ss += __shfl_xor(ss, off);
  __shared__ float wsum[4];
  int lane = tid & 63, wid = tid >> 6;
  if (lane == 0) wsum[wid] = ss;
  __syncthreads();
  float tot = wsum[0] + wsum[1] + wsum[2] + wsum[3];
  float inv = rsqrtf(tot * (1.f / 1024.f) + 1e-6f);
  float4 wl = ((const float4*)w)[tid];
  bf16x4 o;
  o[0] = (__bf16)(v.x * inv * wl.x);
  o[1] = (__bf16)(v.y * inv * wl.y);
  o[2] = (__bf16)(v.z * inv * wl.z);
  o[3] = (__bf16)(v.w * inv * wl.w);
  *(bf16x4*)(hbf + (size_t)r * DM + tid * 4) = o;
}

// ---------------- 8-phase MFMA GEMM: A[M][K] bf16, Bt[N][K] bf16, BK=64
// LDS tiles stored as [rows][64] bf16 with 16B-slot XOR swizzle (slot ^= row&7).
// Staged via global_load_lds (linear LDS dest, inverse-swizzled global source).

template <int ROWS>
__device__ __forceinline__ void stage_tile(const __bf16* __restrict__ src, int ld,
                                           int row0, int kt, __bf16* lbuf, int tid) {
#pragma unroll
  for (int j = 0; j < ROWS / 64; ++j) {
    int off16 = tid + j * 512;          // 16B-chunk index (512 threads)
    int row = off16 >> 3;
    int slot = off16 & 7;
    int l = slot ^ (row & 7);           // inverse swizzle on the SOURCE
    gload16(&src[(size_t)(row0 + row) * ld + kt + l * 8], lbuf + off16 * 8);
  }
}

__device__ __forceinline__ bf16x8 fragrd(const __bf16* buf, int row, int ks, int lane) {
  int slot = ((ks << 2) + (lane >> 4)) ^ (row & 7);   // swizzled read
  return *(const bf16x8*)&buf[(row << 6) + (slot << 3)];
}

template <int BM, int BN, int WM, int WN, int EPI>
__global__ __launch_bounds__(512, 2) void gemm8p(
    const __bf16* __restrict__ A, const __bf16* __restrict__ Bt,
    int N_out, int K,
    const float* __restrict__ gate_bias, const float* __restrict__ shortcut,
    float* __restrict__ outf, __bf16* __restrict__ zbf, float* __restrict__ xf,
    float* __restrict__ gf, __bf16* __restrict__ qbf, float* __restrict__ kf) {
  constexpr int M_REP = BM / (WM * 16);
  constexpr int N_REP = BN / (WN * 16);
  constexpr int MH = M_REP / 2;
  __shared__ __bf16 As[2][BM * 64];
  __shared__ __bf16 Bs[2][BN * 64];

  const int tid = threadIdx.x;
  const int lane = tid & 63;
  const int wid = tid >> 6;
  const int wr = wid / WN, wc = wid % WN;

  // XCD-aware swizzle (grid size is a multiple of 8)
  const int nwg = gridDim.x;
  const int cpx = nwg >> 3;
  const int swz = (blockIdx.x & 7) * cpx + (blockIdx.x >> 3);
  const int ntx = N_out / BN;
  const int m0 = (swz / ntx) * BM;
  const int n0 = (swz % ntx) * BN;

  f32x4 acc[M_REP][N_REP] = {};
  const int NT = K >> 6;

  stage_tile<BM>(A, K, m0, 0, &As[0][0], tid);
  stage_tile<BN>(Bt, K, n0, 0, &Bs[0][0], tid);
  asm volatile("s_waitcnt vmcnt(0)" ::: "memory");
  __builtin_amdgcn_s_barrier();

  for (int t = 0; t < NT; ++t) {
    const __bf16* Ap = &As[t & 1][0];
    const __bf16* Bp = &Bs[t & 1][0];
    __bf16* Aq = &As[(t + 1) & 1][0];
    __bf16* Bq = &Bs[(t + 1) & 1][0];
    const bool pre = (t + 1 < NT);
    const int ktn = (t + 1) << 6;
    const int arow = wr * (M_REP * 16) + (lane & 15);
    const int brow = wc * (N_REP * 16) + (lane & 15);

    bf16x8 a[MH], bb[N_REP];

    // ---- P0: ks=0, m-half 0  (+ prefetch A tile t+1)
#pragma unroll
    for (int m = 0; m < MH; ++m) a[m] = fragrd(Ap, arow + m * 16, 0, lane);
#pragma unroll
    for (int n = 0; n < N_REP; ++n) bb[n] = fragrd(Bp, brow + n * 16, 0, lane);
    if (pre) stage_tile<BM>(A, K, m0, ktn, Aq, tid);
    __builtin_amdgcn_s_barrier();
    __builtin_amdgcn_s_setprio(1);
#pragma unroll
    for (int m = 0; m < MH; ++m)
#pragma unroll
      for (int n = 0; n < N_REP; ++n)
        acc[m][n] = __builtin_amdgcn_mfma_f32_16x16x32_bf16(a[m], bb[n], acc[m][n], 0, 0, 0);
    __builtin_amdgcn_s_setprio(0);
    __builtin_amdgcn_s_barrier();

    // ---- P1: ks=0, m-half 1  (+ prefetch B tile t+1)
#pragma unroll
    for (int m = 0; m < MH; ++m) a[m] = fragrd(Ap, arow + (MH + m) * 16, 0, lane);
    if (pre) stage_tile<BN>(Bt, K, n0, ktn, Bq, tid);
    __builtin_amdgcn_s_barrier();
    __builtin_amdgcn_s_setprio(1);
#pragma unroll
    for (int m = 0; m < MH; ++m)
#pragma unroll
      for (int n = 0; n < N_REP; ++n)
        acc[MH + m][n] = __builtin_amdgcn_mfma_f32_16x16x32_bf16(a[m], bb[n], acc[MH + m][n], 0, 0, 0);
    __builtin_amdgcn_s_setprio(0);
    __builtin_amdgcn_s_barrier();

    // ---- P2: ks=1, m-half 0
#pragma unroll
    for (int m = 0; m < MH; ++m) a[m] = fragrd(Ap, arow + m * 16, 1, lane);
#pragma unroll
    for (int n = 0; n < N_REP; ++n) bb[n] = fragrd(Bp, brow + n * 16, 1, lane);
    __builtin_amdgcn_s_barrier();
    __builtin_amdgcn_s_setprio(1);
#pragma unroll
    for (int m = 0; m < MH; ++m)
#pragma unroll
      for (int n = 0; n < N_REP; ++n)
        acc[m][n] = __builtin_amdgcn_mfma_f32_16x16x32_bf16(a[m], bb[n], acc[m][n], 0, 0, 0);
    __builtin_amdgcn_s_setprio(0);
    __builtin_amdgcn_s_barrier();

    // ---- P3: ks=1, m-half 1  (+ counted drain before buffer handoff)
#pragma unroll
    for (int m = 0; m < MH; ++m) a[m] = fragrd(Ap, arow + (MH + m) * 16, 1, lane);
    __builtin_amdgcn_s_barrier();
    __builtin_amdgcn_s_setprio(1);
#pragma unroll
    for (int m = 0; m < MH; ++m)
#pragma unroll
      for (int n = 0; n < N_REP; ++n)
        acc[MH + m][n] = __builtin_amdgcn_mfma_f32_16x16x32_bf16(a[m], bb[n], acc[MH + m][n], 0, 0, 0);
    __builtin_amdgcn_s_setprio(0);
    if (pre) asm volatile("s_waitcnt vmcnt(0)" ::: "memory");
    __builtin_amdgcn_s_barrier();
  }

  // epilogue
#pragma unroll
  for (int m = 0; m < M_REP; ++m) {
#pragma unroll
    for (int n = 0; n < N_REP; ++n) {
#pragma unroll
      for (int i = 0; i < 4; ++i) {
        int r = m0 + wr * (M_REP * 16) + m * 16 + ((lane >> 4) << 2) + i;
        int c = n0 + wc * (N_REP * 16) + n * 16 + (lane & 15);
        float v = acc[m][n][i];
        if (EPI == 1) {
          if (c < 1024)       zbf[(size_t)r * DM + c] = (__bf16)sigmoidf(v);
          else if (c < 2048)  xf[(size_t)r * DM + (c - 1024)] = v;
          else if (c < 3072)  gf[(size_t)r * DM + (c - 2048)] = sigmoidf(v + gate_bias[c - 2048]);
          else if (c < 3200)  qbf[(size_t)r * 128 + (c - 3072)] = (__bf16)v;
          else                kf[(size_t)r * 128 + (c - 3200)] = v;
        } else {
          outf[(size_t)r * DM + c] = v + shortcut[(size_t)r * DM + c];
        }
      }
    }
  }
}

// ---------------- per-chunk first-order scan (f32 state), thread = one d-channel
__global__ __launch_bounds__(256) void scan_kernel(const float* __restrict__ g,
                                                   const float* __restrict__ x,
                                                   const float* __restrict__ kraw,
                                                   __bf16* __restrict__ ixa,
                                                   __bf16* __restrict__ ika) {
  int bx = blockIdx.x;            // 2*64*4 = 512 blocks
  int part = bx & 3;
  int c = (bx >> 2) & 63;
  int b = bx >> 8;
  int d = part * 256 + threadIdx.x;
  size_t base = (size_t)b * SEQ + (size_t)c * 64;
  float sx = 0.f, sk = 0.f;
  for (int t = 0; t < 64; ++t) {
    size_t row = base + t;
    float gg = g[row * DM + d];
    float xv = x[row * DM + d];
    float kv = kraw[row * 128 + (d & 127)];
    sx = gg * (sx - xv) + xv;   // = g*prev + (1-g)*x
    sk = gg * (sk - kv) + kv;
    ixa[row * DM + d] = (__bf16)sx;
    ika[row * DM + d] = (__bf16)sk;
  }
}

// ---------------- attention: block = (qtile 64 queries, head, batch); 4 waves
__global__ __launch_bounds__(256) void attn_kernel(const __bf16* __restrict__ qbf,
                                                   const __bf16* __restrict__ ixa,
                                                   const __bf16* __restrict__ ika,
                                                   const __bf16* __restrict__ zbf,
                                                   __bf16* __restrict__ y) {
  const int qt = blockIdx.x;   // 0..63 query chunk
  const int h  = blockIdx.y;   // 0..15
  const int b  = blockIdx.z;   // 0..1
  const int tid = threadIdx.x;
  const int lane = tid & 63, wd = tid >> 6;

  __shared__ __bf16 qs[64 * 72];
  __shared__ __bf16 ck[64 * 72];
  __shared__ __bf16 cxT[64 * 72];
  __shared__ __bf16 pb[64 * 72];
  __shared__ float sc[64 * 65];
  __shared__ float rden[64], iwd[64];

  const size_t base = (size_t)b * SEQ;

  for (int i = tid; i < 512; i += 256) {
    int row = i >> 3, part = i & 7;
    *(bf16x8*)&qs[row * 72 + part * 8] =
        *(const bf16x8*)&qbf[(base + qt * 64 + row) * 128 + (h & 1) * 64 + part * 8];
    *(bf16x8*)&ck[row * 72 + part * 8] =
        *(const bf16x8*)&ika[(base + (size_t)row * 64) * DM + h * 64 + part * 8];
  }
  for (int i = tid; i < 4096; i += 256) {
    int c = i & 63, j = i >> 6;
    cxT[j * 72 + c] = ixa[(base + (size_t)c * 64) * DM + h * 64 + j];
  }
  __syncthreads();

  {
    f32x4 d4[4] = {};
#pragma unroll
    for (int kk = 0; kk < 64; kk += 32) {
      bf16x8 a = *(const bf16x8*)&qs[(wd * 16 + (lane & 15)) * 72 + kk + (lane >> 4) * 8];
#pragma unroll
      for (int ni = 0; ni < 4; ++ni) {
        bf16x8 bb = *(const bf16x8*)&ck[(ni * 16 + (lane & 15)) * 72 + kk + (lane >> 4) * 8];
        d4[ni] = __builtin_amdgcn_mfma_f32_16x16x32_bf16(a, bb, d4[ni], 0, 0, 0);
      }
    }
#pragma unroll
    for (int ni = 0; ni < 4; ++ni)
#pragma unroll
      for (int i = 0; i < 4; ++i) {
        int qrow = wd * 16 + (lane >> 4) * 4 + i;
        int c = ni * 16 + (lane & 15);
        sc[qrow * 65 + c] = 0.125f * d4[ni][i];
      }
  }

  float lse = 0.f;
  if (tid < 64) {
    const __bf16* qrow = &qbf[(base + qt * 64 + tid) * 128 + (h & 1) * 64];
    const __bf16* krow = &ika[(base + qt * 64 + tid) * DM + h * 64];
    float dot = 0.f;
#pragma unroll
    for (int p = 0; p < 8; ++p) {
      bf16x8 qa = *(const bf16x8*)&qrow[p * 8];
      bf16x8 ka = *(const bf16x8*)&krow[p * 8];
#pragma unroll
      for (int e = 0; e < 8; ++e) dot += (float)qa[e] * (float)ka[e];
    }
    lse = 0.125f * dot;
  }
  __syncthreads();

  if (tid < 64) {
    int q = tid;
    float m = lse;
    for (int c = 0; c < qt; ++c) m = fmaxf(m, sc[q * 65 + c]);
    float den = 0.f;
    for (int c = 0; c < 64; ++c) {
      float wv = (c < qt) ? __expf(sc[q * 65 + c] - m) : 0.f;
      pb[q * 72 + c] = (__bf16)wv;
      den += wv;
    }
    float iw = __expf(lse - m);
    den += iw;
    rden[q] = 1.f / den;
    iwd[q] = iw;
  }
  __syncthreads();

  {
    f32x4 d4[4] = {};
#pragma unroll
    for (int kk = 0; kk < 64; kk += 32) {
      bf16x8 a = *(const bf16x8*)&pb[(wd * 16 + (lane & 15)) * 72 + kk + (lane >> 4) * 8];
#pragma unroll
      for (int ni = 0; ni < 4; ++ni) {
        bf16x8 bb = *(const bf16x8*)&cxT[(ni * 16 + (lane & 15)) * 72 + kk + (lane >> 4) * 8];
        d4[ni] = __builtin_amdgcn_mfma_f32_16x16x32_bf16(a, bb, d4[ni], 0, 0, 0);
      }
    }
#pragma unroll
    for (int ni = 0; ni < 4; ++ni)
#pragma unroll
      for (int i = 0; i < 4; ++i) {
        int qrow = wd * 16 + (lane >> 4) * 4 + i;
        int j = ni * 16 + (lane & 15);
        size_t srow = base + qt * 64 + qrow;
        float ix = (float)ixa[srow * DM + h * 64 + j];
        float outv = (d4[ni][i] + iwd[qrow] * ix) * rden[qrow];
        float zv = (float)zbf[srow * DM + h * 64 + j];
        y[srow * DM + h * 64 + j] = (__bf16)(outv * zv);
      }
  }
}

// ---------------- launcher
extern "C" void kernel_launch(void* const* d_in, const int* in_sizes, int n_in,
                              void* d_out, int out_size, void* d_ws, size_t ws_size,
                              hipStream_t stream) {
  const float* hidden = (const float*)d_in[0];
  const float* rmsw   = (const float*)d_in[1];
  const float* Win    = (const float*)d_in[2];
  const float* gbias  = (const float*)d_in[3];
  const float* Wout   = (const float*)d_in[4];
  float* out = (float*)d_out;

  char* ws = (char*)d_ws;
  size_t o = 0;
  auto alloc = [&](size_t bytes) { char* p = ws + o; o += (bytes + 255) & ~(size_t)255; return p; };
  __bf16* WinT  = (__bf16*)alloc((size_t)PD * DM * 2);
  __bf16* WoutT = (__bf16*)alloc((size_t)DM * DM * 2);
  __bf16* hy    = (__bf16*)alloc((size_t)TROWS * DM * 2);  // h_bf, reused as y after GEMM1
  __bf16* zbf   = (__bf16*)alloc((size_t)TROWS * DM * 2);
  float*  xf    = (float*)alloc((size_t)TROWS * DM * 4);
  float*  gf    = (float*)alloc((size_t)TROWS * DM * 4);
  __bf16* qbf   = (__bf16*)alloc((size_t)TROWS * 128 * 2);
  float*  kf    = (float*)alloc((size_t)TROWS * 128 * 4);
  __bf16* ixa   = (__bf16*)alloc((size_t)TROWS * DM * 2);
  __bf16* ika   = (__bf16*)alloc((size_t)TROWS * DM * 2);

  tcvt_kernel<<<dim3(PD / 32, DM / 32), dim3(32, 8), 0, stream>>>(Win, WinT, DM, PD);
  tcvt_kernel<<<dim3(DM / 32, DM / 32), dim3(32, 8), 0, stream>>>(Wout, WoutT, DM, DM);
  rmsnorm_kernel<<<TROWS, 256, 0, stream>>>(hidden, rmsw, hy);
  // GEMM1: M=8192, N=3328, K=1024 -> 32x13 = 416 tiles (416 % 8 == 0)
  gemm8p<256, 256, 2, 4, 1><<<dim3((TROWS / 256) * (PD / 256)), 512, 0, stream>>>(
      hy, WinT, PD, DM, gbias, nullptr, nullptr, zbf, xf, gf, qbf, kf);
  scan_kernel<<<512, 256, 0, stream>>>(gf, xf, kf, ixa, ika);
  attn_kernel<<<dim3(64, 16, 2), 256, 0, stream>>>(qbf, ixa, ika, zbf, hy);
  // GEMM2: M=8192, N=1024, K=1024 -> 32x8 = 256 tiles (256 % 8 == 0)
  gemm8p<256, 128, 4, 2, 0><<<dim3((TROWS / 256) * (DM / 128)), 512, 0, stream>>>(
      hy, WoutT, DM, DM, nullptr, hidden, out, nullptr, nullptr, nullptr, nullptr, nullptr);
}

// Round 3
// 217.378 us; speedup vs baseline: 1.1122x; 1.0301x over previous
//
#include <hip/hip_runtime.h>
#include <hip/hip_bf16.h>

typedef __bf16 bf16x8 __attribute__((ext_vector_type(8)));
typedef __bf16 bf16x4 __attribute__((ext_vector_type(4)));
typedef float  f32x4  __attribute__((ext_vector_type(4)));

#define DM 1024
#define PD 3328
#define TROWS 8192   // bs*seq = 2*4096
#define SEQ 4096

__device__ __forceinline__ float sigmoidf(float x) { return 1.f / (1.f + __expf(-x)); }

__device__ __forceinline__ void gload16(const void* g, void* l) {
  __builtin_amdgcn_global_load_lds(
      (const __attribute__((address_space(1))) void*)g,
      (__attribute__((address_space(3))) void*)l, 16, 0, 0);
}

// ---------------- transpose + f32->bf16 convert:  in[K][N] f32 -> out[N][K] bf16
__global__ __launch_bounds__(256) void tcvt_kernel(const float* __restrict__ in,
                                                   __bf16* __restrict__ out,
                                                   int K, int N) {
  __shared__ float tile[32][33];
  int n0 = blockIdx.x * 32, k0 = blockIdx.y * 32;
  int tx = threadIdx.x, ty = threadIdx.y;     // 32 x 8
  for (int i = ty; i < 32; i += 8) tile[i][tx] = in[(size_t)(k0 + i) * N + n0 + tx];
  __syncthreads();
  for (int i = ty; i < 32; i += 8) out[(size_t)(n0 + i) * K + k0 + tx] = (__bf16)tile[tx][i];
}

// ---------------- RMSNorm -> bf16
__global__ __launch_bounds__(256) void rmsnorm_kernel(const float* __restrict__ hidden,
                                                      const float* __restrict__ w,
                                                      __bf16* __restrict__ hbf) {
  int r = blockIdx.x;
  int tid = threadIdx.x;
  float4 v = ((const float4*)(hidden + (size_t)r * DM))[tid];
  float ss = v.x * v.x + v.y * v.y + v.z * v.z + v.w * v.w;
#pragma unroll
  for (int off = 32; off > 0; off >>= 1) ss += __shfl_xor(ss, off);
  __shared__ float wsum[4];
  int lane = tid & 63, wid = tid >> 6;
  if (lane == 0) wsum[wid] = ss;
  __syncthreads();
  float tot = wsum[0] + wsum[1] + wsum[2] + wsum[3];
  float inv = rsqrtf(tot * (1.f / 1024.f) + 1e-6f);
  float4 wl = ((const float4*)w)[tid];
  bf16x4 o;
  o[0] = (__bf16)(v.x * inv * wl.x);
  o[1] = (__bf16)(v.y * inv * wl.y);
  o[2] = (__bf16)(v.z * inv * wl.z);
  o[3] = (__bf16)(v.w * inv * wl.w);
  *(bf16x4*)(hbf + (size_t)r * DM + tid * 4) = o;
}

// ---------------- ring-4 pipelined MFMA GEMM, BK=32.
// A[M][K] bf16, Bt[N][K] bf16. LDS tile rows are 32 elems (64 B) -> the
// 16-row x 4-slot fragment read pattern is uniformly spread over banks
// (8 accesses/bank = ds_read_b128 minimum), no swizzle needed.
// Pipeline: compute(t) reads buf[t%4]; tiles t+1,t+2 in flight; stage(t+3)
// issued during compute(t) into buf[(t+3)%4] == buf[(t-1)%4] (safe: all
// reads of t-1 completed before the barrier that precedes the issue).
// Boundary wait: counted vmcnt(2 tiles worth), never 0 in the main loop.
template <int BM, int BN, int WM, int WN, int EPI>
__global__ __launch_bounds__(512, 2) void gemm32(
    const __bf16* __restrict__ A, const __bf16* __restrict__ Bt,
    int N_out, int K,
    const float* __restrict__ gate_bias, const float* __restrict__ shortcut,
    float* __restrict__ outf, __bf16* __restrict__ zbf, __bf16* __restrict__ xbf,
    float* __restrict__ gf, __bf16* __restrict__ qbf, __bf16* __restrict__ kbf) {
  constexpr int M_REP = BM / (WM * 16);
  constexpr int N_REP = BN / (WN * 16);
  constexpr int PH = (M_REP * N_REP) / 16;   // phases per K-tile (16 MFMA each)
  constexpr int MPP = M_REP / PH;
  constexpr int LA = BM / 128;               // gload16 per thread per A-chunk
  constexpr int LB = BN / 128;
  constexpr int WAIT2 = 2 * (LA + LB);       // 2 tiles of loads outstanding

  __shared__ __bf16 As[4][BM * 32];
  __shared__ __bf16 Bs[4][BN * 32];

  const int tid = threadIdx.x;
  const int lane = tid & 63;
  const int wid = tid >> 6;
  const int wr = wid / WN, wc = wid % WN;

  // XCD-aware swizzle (grid sizes are multiples of 8)
  const int nwg = gridDim.x;
  const int cpx = nwg >> 3;
  const int swz = (blockIdx.x & 7) * cpx + (blockIdx.x >> 3);
  const int ntx = N_out / BN;
  const int m0 = (swz / ntx) * BM;
  const int n0 = (swz % ntx) * BN;

  f32x4 acc[M_REP][N_REP] = {};
  const int NT = K >> 5;

  const int arow0 = wr * (M_REP * 16) + (lane & 15);
  const int brow0 = wc * (N_REP * 16) + (lane & 15);
  const int ko = (lane >> 4) * 8;   // k offset within the 32-wide tile

  auto stageA = [&](int t) {
    __bf16* dst = &As[t & 3][0];
    const int kt = t << 5;
#pragma unroll
    for (int j = 0; j < LA; ++j) {
      int off16 = tid + j * 512;
      int row = off16 >> 2, slot = off16 & 3;
      gload16(&A[(size_t)(m0 + row) * K + kt + slot * 8], dst + off16 * 8);
    }
  };
  auto stageB = [&](int t) {
    __bf16* dst = &Bs[t & 3][0];
    const int kt = t << 5;
#pragma unroll
    for (int j = 0; j < LB; ++j) {
      int off16 = tid + j * 512;
      int row = off16 >> 2, slot = off16 & 3;
      gload16(&Bt[(size_t)(n0 + row) * K + kt + slot * 8], dst + off16 * 8);
    }
  };

  // prologue: 3 tiles in flight, wait for tile 0 only (2 tiles stay in flight)
  stageA(0); stageB(0); stageA(1); stageB(1); stageA(2); stageB(2);
  if constexpr (WAIT2 == 8) asm volatile("s_waitcnt vmcnt(8)" ::: "memory");
  else                      asm volatile("s_waitcnt vmcnt(6)" ::: "memory");
  __builtin_amdgcn_s_barrier();
  asm volatile("" ::: "memory");

  for (int t = 0; t < NT; ++t) {
    const __bf16* Ap = &As[t & 3][0];
    const __bf16* Bp = &Bs[t & 3][0];
    const bool pre = (t + 3 < NT);
    bf16x8 bfr[N_REP];
#pragma unroll
    for (int n = 0; n < N_REP; ++n)
      bfr[n] = *(const bf16x8*)&Bp[(brow0 + n * 16) * 32 + ko];
#pragma unroll
    for (int ph = 0; ph < PH; ++ph) {
      bf16x8 afr[MPP];
#pragma unroll
      for (int m = 0; m < MPP; ++m)
        afr[m] = *(const bf16x8*)&Ap[(arow0 + (ph * MPP + m) * 16) * 32 + ko];
      if (pre) {
        if (PH == 1)      { stageA(t + 3); stageB(t + 3); }
        else if (ph == 0) stageA(t + 3);
        else              stageB(t + 3);
      }
      __builtin_amdgcn_s_setprio(1);
#pragma unroll
      for (int m = 0; m < MPP; ++m)
#pragma unroll
        for (int n = 0; n < N_REP; ++n)
          acc[ph * MPP + m][n] = __builtin_amdgcn_mfma_f32_16x16x32_bf16(
              afr[m], bfr[n], acc[ph * MPP + m][n], 0, 0, 0);
      __builtin_amdgcn_s_setprio(0);
      if (ph == PH - 1) {
        if (t < NT - 3) {
          // need tile t+1 landed; tiles t+2, t+3 (WAIT2 loads) may stay in flight
          if constexpr (WAIT2 == 8) asm volatile("s_waitcnt vmcnt(8)" ::: "memory");
          else                      asm volatile("s_waitcnt vmcnt(6)" ::: "memory");
        } else if (t < NT - 1) {
          asm volatile("s_waitcnt vmcnt(0)" ::: "memory");   // tail tiles only
        }
      }
      __builtin_amdgcn_s_barrier();
      asm volatile("" ::: "memory");
    }
  }

  // epilogue
#pragma unroll
  for (int m = 0; m < M_REP; ++m) {
#pragma unroll
    for (int n = 0; n < N_REP; ++n) {
#pragma unroll
      for (int i = 0; i < 4; ++i) {
        int r = m0 + wr * (M_REP * 16) + m * 16 + ((lane >> 4) << 2) + i;
        int c = n0 + wc * (N_REP * 16) + n * 16 + (lane & 15);
        float v = acc[m][n][i];
        if (EPI == 1) {
          if (c < 1024)       zbf[(size_t)r * DM + c] = (__bf16)sigmoidf(v);
          else if (c < 2048)  xbf[(size_t)r * DM + (c - 1024)] = (__bf16)v;
          else if (c < 3072)  gf[(size_t)r * DM + (c - 2048)] = sigmoidf(v + gate_bias[c - 2048]);
          else if (c < 3200)  qbf[(size_t)r * 128 + (c - 3072)] = (__bf16)v;
          else                kbf[(size_t)r * 128 + (c - 3200)] = (__bf16)v;
        } else {
          outf[(size_t)r * DM + c] = v + shortcut[(size_t)r * DM + c];
        }
      }
    }
  }
}

// ---------------- per-chunk first-order scan (f32 state), thread = one d-channel
__global__ __launch_bounds__(256) void scan_kernel(const float* __restrict__ g,
                                                   const __bf16* __restrict__ x,
                                                   const __bf16* __restrict__ kin,
                                                   __bf16* __restrict__ ixa,
                                                   __bf16* __restrict__ ika) {
  int bx = blockIdx.x;            // 2*64*4 = 512 blocks
  int part = bx & 3;
  int c = (bx >> 2) & 63;
  int b = bx >> 8;
  int d = part * 256 + threadIdx.x;
  size_t base = (size_t)b * SEQ + (size_t)c * 64;
  float sx = 0.f, sk = 0.f;
  for (int t = 0; t < 64; ++t) {
    size_t row = base + t;
    float gg = g[row * DM + d];
    float xv = (float)x[row * DM + d];
    float kv = (float)kin[row * 128 + (d & 127)];
    sx = gg * (sx - xv) + xv;   // = g*prev + (1-g)*x
    sk = gg * (sk - kv) + kv;
    ixa[row * DM + d] = (__bf16)sx;
    ika[row * DM + d] = (__bf16)sk;
  }
}

// ---------------- attention: block = (qtile 64 queries, head, batch); 4 waves
__global__ __launch_bounds__(256) void attn_kernel(const __bf16* __restrict__ qbf,
                                                   const __bf16* __restrict__ ixa,
                                                   const __bf16* __restrict__ ika,
                                                   const __bf16* __restrict__ zbf,
                                                   __bf16* __restrict__ y) {
  const int qt = blockIdx.x;   // 0..63 query chunk
  const int h  = blockIdx.y;   // 0..15
  const int b  = blockIdx.z;   // 0..1
  const int tid = threadIdx.x;
  const int lane = tid & 63, wd = tid >> 6;

  __shared__ __bf16 qs[64 * 72];
  __shared__ __bf16 ck[64 * 72];
  __shared__ __bf16 cxT[64 * 72];
  __shared__ __bf16 pb[64 * 72];
  __shared__ float sc[64 * 65];
  __shared__ float rden[64], iwd[64];

  const size_t base = (size_t)b * SEQ;

  for (int i = tid; i < 512; i += 256) {
    int row = i >> 3, part = i & 7;
    *(bf16x8*)&qs[row * 72 + part * 8] =
        *(const bf16x8*)&qbf[(base + qt * 64 + row) * 128 + (h & 1) * 64 + part * 8];
    *(bf16x8*)&ck[row * 72 + part * 8] =
        *(const bf16x8*)&ika[(base + (size_t)row * 64) * DM + h * 64 + part * 8];
  }
  for (int i = tid; i < 4096; i += 256) {
    int c = i & 63, j = i >> 6;
    cxT[j * 72 + c] = ixa[(base + (size_t)c * 64) * DM + h * 64 + j];
  }
  __syncthreads();

  {
    f32x4 d4[4] = {};
#pragma unroll
    for (int kk = 0; kk < 64; kk += 32) {
      bf16x8 a = *(const bf16x8*)&qs[(wd * 16 + (lane & 15)) * 72 + kk + (lane >> 4) * 8];
#pragma unroll
      for (int ni = 0; ni < 4; ++ni) {
        bf16x8 bb = *(const bf16x8*)&ck[(ni * 16 + (lane & 15)) * 72 + kk + (lane >> 4) * 8];
        d4[ni] = __builtin_amdgcn_mfma_f32_16x16x32_bf16(a, bb, d4[ni], 0, 0, 0);
      }
    }
#pragma unroll
    for (int ni = 0; ni < 4; ++ni)
#pragma unroll
      for (int i = 0; i < 4; ++i) {
        int qrow = wd * 16 + (lane >> 4) * 4 + i;
        int c = ni * 16 + (lane & 15);
        sc[qrow * 65 + c] = 0.125f * d4[ni][i];
      }
  }

  float lse = 0.f;
  if (tid < 64) {
    const __bf16* qrow = &qbf[(base + qt * 64 + tid) * 128 + (h & 1) * 64];
    const __bf16* krow = &ika[(base + qt * 64 + tid) * DM + h * 64];
    float dot = 0.f;
#pragma unroll
    for (int p = 0; p < 8; ++p) {
      bf16x8 qa = *(const bf16x8*)&qrow[p * 8];
      bf16x8 ka = *(const bf16x8*)&krow[p * 8];
#pragma unroll
      for (int e = 0; e < 8; ++e) dot += (float)qa[e] * (float)ka[e];
    }
    lse = 0.125f * dot;
  }
  __syncthreads();

  if (tid < 64) {
    int q = tid;
    float m = lse;
    for (int c = 0; c < qt; ++c) m = fmaxf(m, sc[q * 65 + c]);
    float den = 0.f;
    for (int c = 0; c < 64; ++c) {
      float wv = (c < qt) ? __expf(sc[q * 65 + c] - m) : 0.f;
      pb[q * 72 + c] = (__bf16)wv;
      den += wv;
    }
    float iw = __expf(lse - m);
    den += iw;
    rden[q] = 1.f / den;
    iwd[q] = iw;
  }
  __syncthreads();

  {
    f32x4 d4[4] = {};
#pragma unroll
    for (int kk = 0; kk < 64; kk += 32) {
      bf16x8 a = *(const bf16x8*)&pb[(wd * 16 + (lane & 15)) * 72 + kk + (lane >> 4) * 8];
#pragma unroll
      for (int ni = 0; ni < 4; ++ni) {
        bf16x8 bb = *(const bf16x8*)&cxT[(ni * 16 + (lane & 15)) * 72 + kk + (lane >> 4) * 8];
        d4[ni] = __builtin_amdgcn_mfma_f32_16x16x32_bf16(a, bb, d4[ni], 0, 0, 0);
      }
    }
#pragma unroll
    for (int ni = 0; ni < 4; ++ni)
#pragma unroll
      for (int i = 0; i < 4; ++i) {
        int qrow = wd * 16 + (lane >> 4) * 4 + i;
        int j = ni * 16 + (lane & 15);
        size_t srow = base + qt * 64 + qrow;
        float ix = (float)ixa[srow * DM + h * 64 + j];
        float outv = (d4[ni][i] + iwd[qrow] * ix) * rden[qrow];
        float zv = (float)zbf[srow * DM + h * 64 + j];
        y[srow * DM + h * 64 + j] = (__bf16)(outv * zv);
      }
  }
}

// ---------------- launcher
extern "C" void kernel_launch(void* const* d_in, const int* in_sizes, int n_in,
                              void* d_out, int out_size, void* d_ws, size_t ws_size,
                              hipStream_t stream) {
  const float* hidden = (const float*)d_in[0];
  const float* rmsw   = (const float*)d_in[1];
  const float* Win    = (const float*)d_in[2];
  const float* gbias  = (const float*)d_in[3];
  const float* Wout   = (const float*)d_in[4];
  float* out = (float*)d_out;

  char* ws = (char*)d_ws;
  size_t o = 0;
  auto alloc = [&](size_t bytes) { char* p = ws + o; o += (bytes + 255) & ~(size_t)255; return p; };
  __bf16* WinT  = (__bf16*)alloc((size_t)PD * DM * 2);
  __bf16* WoutT = (__bf16*)alloc((size_t)DM * DM * 2);
  __bf16* hy    = (__bf16*)alloc((size_t)TROWS * DM * 2);  // h_bf, reused as y after GEMM1
  __bf16* zbf   = (__bf16*)alloc((size_t)TROWS * DM * 2);
  __bf16* xbf   = (__bf16*)alloc((size_t)TROWS * DM * 2);
  float*  gf    = (float*)alloc((size_t)TROWS * DM * 4);
  __bf16* qbf   = (__bf16*)alloc((size_t)TROWS * 128 * 2);
  __bf16* kbf   = (__bf16*)alloc((size_t)TROWS * 128 * 2);
  __bf16* ixa   = (__bf16*)alloc((size_t)TROWS * DM * 2);
  __bf16* ika   = (__bf16*)alloc((size_t)TROWS * DM * 2);

  tcvt_kernel<<<dim3(PD / 32, DM / 32), dim3(32, 8), 0, stream>>>(Win, WinT, DM, PD);
  tcvt_kernel<<<dim3(DM / 32, DM / 32), dim3(32, 8), 0, stream>>>(Wout, WoutT, DM, DM);
  rmsnorm_kernel<<<TROWS, 256, 0, stream>>>(hidden, rmsw, hy);
  // GEMM1: M=8192, N=3328, K=1024 -> 32x13 = 416 blocks (416 % 8 == 0)
  gemm32<256, 256, 2, 4, 1><<<dim3((TROWS / 256) * (PD / 256)), 512, 0, stream>>>(
      hy, WinT, PD, DM, gbias, nullptr, nullptr, zbf, xbf, gf, qbf, kbf);
  scan_kernel<<<512, 256, 0, stream>>>(gf, xbf, kbf, ixa, ika);
  attn_kernel<<<dim3(64, 16, 2), 256, 0, stream>>>(qbf, ixa, ika, zbf, hy);
  // GEMM2: M=8192, N=1024, K=1024 -> 32x8 = 256 blocks (1 per CU)
  gemm32<256, 128, 4, 2, 0><<<dim3((TROWS / 256) * (DM / 128)), 512, 0, stream>>>(
      hy, WoutT, DM, DM, nullptr, hidden, out, nullptr, nullptr, nullptr, nullptr, nullptr);
}